// Round 11
// baseline (1034.904 us; speedup 1.0000x reference)
//
#include <hip/hip_runtime.h>

#define B_TOTAL   8192
#define CR_LEN    168
#define PR_LEN    24
#define HID       40
#define ROWS      4            // rows per block
#define NTHREADS  320          // 4 rows x 40 units x 2 k-halves
#define XC_LEN    ((CR_LEN + PR_LEN) * 3)   // 576
#define OUT_STRIDE (B_TOTAL * PR_LEN)       // 196608

__device__ __forceinline__ float fast_rcp(float x) { return __builtin_amdgcn_rcpf(x); }

__device__ __forceinline__ float sigmoid_f(float x) {
    return fast_rcp(1.0f + __expf(-x));
}

__device__ __forceinline__ float tanh_f(float x) {
    float ax = fabsf(x);
    float e  = __expf(-2.0f * ax);
    float r  = (1.0f - e) * fast_rcp(1.0f + e);
    return copysignf(r, x);
}

__device__ __forceinline__ unsigned rotl32(unsigned x, int d) {
    return (x << d) | (x >> (32 - d));
}

// JAX threefry2x32 (20 rounds) — HW-KAT-verified (round 2)
__device__ __forceinline__ void threefry2x32(unsigned k0, unsigned k1,
                                             unsigned c0, unsigned c1,
                                             unsigned& o0, unsigned& o1) {
    const unsigned k2 = 0x1BD11BDAu ^ k0 ^ k1;
    unsigned x0 = c0 + k0, x1 = c1 + k1;
#define TF_R(rr) { x0 += x1; x1 = rotl32(x1, (rr)); x1 ^= x0; }
    TF_R(13) TF_R(15) TF_R(26) TF_R(6)  x0 += k1; x1 += k2 + 1u;
    TF_R(17) TF_R(29) TF_R(16) TF_R(24) x0 += k2; x1 += k0 + 2u;
    TF_R(13) TF_R(15) TF_R(26) TF_R(6)  x0 += k0; x1 += k1 + 3u;
    TF_R(17) TF_R(29) TF_R(16) TF_R(24) x0 += k1; x1 += k2 + 4u;
    TF_R(13) TF_R(15) TF_R(26) TF_R(6)  x0 += k2; x1 += k0 + 5u;
#undef TF_R
    o0 = x0; o1 = x1;
}

// Giles single-precision erfinv (XLA ErfInv32 poly)
__device__ __forceinline__ float erfinv_f(float x) {
    float w = -__logf(fmaf(-x, x, 1.0f));
    float p;
    if (w < 5.0f) {
        w -= 2.5f;
        p = 2.81022636e-08f;
        p = fmaf(p, w, 3.43273939e-07f);
        p = fmaf(p, w, -3.5233877e-06f);
        p = fmaf(p, w, -4.39150654e-06f);
        p = fmaf(p, w, 0.00021858087f);
        p = fmaf(p, w, -0.00125372503f);
        p = fmaf(p, w, -0.00417768164f);
        p = fmaf(p, w, 0.246640727f);
        p = fmaf(p, w, 1.50140941f);
    } else {
        w = sqrtf(w) - 3.0f;
        p = -0.000200214257f;
        p = fmaf(p, w, 0.000100950558f);
        p = fmaf(p, w, 0.00134934322f);
        p = fmaf(p, w, -0.00367342844f);
        p = fmaf(p, w, 0.00573950773f);
        p = fmaf(p, w, -0.0076224613f);
        p = fmaf(p, w, 0.00943887047f);
        p = fmaf(p, w, 1.00167406f);
        p = fmaf(p, w, 2.83297682f);
    }
    return p * x;
}

// KAT tripwire (Random123 vectors)
__device__ __forceinline__ float kat_poison() {
    float poison = 0.0f;
    unsigned o0, o1;
    threefry2x32(0u, 0u, 0u, 0u, o0, o1);
    bool ok1 = (o0 == 0x6b200159u) && (o1 == 0x99ba4efeu);
    threefry2x32(0xFFFFFFFFu, 0xFFFFFFFFu, 0xFFFFFFFFu, 0xFFFFFFFFu, o0, o1);
    bool ok2 = (o0 == 0x1cb996fcu) && (o1 == 0xbb002be7u);
    if (!(ok1 && ok2)) poison += 4096.0f;
    threefry2x32(0x13198a2eu, 0x03707344u, 0x243f6a88u, 0x85a308d3u, o0, o1);
    bool ok3 = (o0 == 0xc4923a9cu) && (o1 == 0x483df7a0u);
    if (!ok3) poison += 8192.0f;
    return poison;
}

// Opaque-pin a loaded quad (param must not be named `w` — R6 lesson).
#define KEEPQ(q) asm volatile("" : "+v"((q).x), "+v"((q).y), "+v"((q).z), "+v"((q).w))

// 4 fma's: acc += dot(w4, h4)
#define DOT4(acc, w4, h4) \
    acc = fmaf((w4).x, (h4).x, acc); acc = fmaf((w4).y, (h4).y, acc); \
    acc = fmaf((w4).z, (h4).z, acc); acc = fmaf((w4).w, (h4).w, acc);

// load 5 named float4 weight quads (one gate row HALF: 20 floats), pin them
#define LOADW5(P, base)                                                        \
    float4 P##0 = pw[(base) + 0], P##1 = pw[(base) + 1],                       \
           P##2 = pw[(base) + 2], P##3 = pw[(base) + 3],                       \
           P##4 = pw[(base) + 4];                                              \
    KEEPQ(P##0); KEEPQ(P##1); KEEPQ(P##2); KEEPQ(P##3); KEEPQ(P##4);

// k-split LSTM step: this thread computes the 4 gate HALF-dots for (row r,
// unit j, k-half h); partner lane (lane^1) holds the other half. One shfl
// per gate combines them. No divergence except the single h-write.
#define KSTEP(XIN0, XIN1) do {                                                 \
    float p0 = fmaf(cA0, (XIN0), bA); p0 = fmaf(cB0, (XIN1), p0);              \
    float p1 = fmaf(cA1, (XIN0), bB); p1 = fmaf(cB1, (XIN1), p1);              \
    float p2 = fmaf(cA2, (XIN0), bC); p2 = fmaf(cB2, (XIN1), p2);              \
    float p3 = fmaf(cA3, (XIN0), bD); p3 = fmaf(cB3, (XIN1), p3);              \
    const float4* hp = (const float4*)&h_s[cur][r][20 * h];                    \
    float4 h4;                                                                 \
    h4 = hp[0]; DOT4(p0, wA0, h4) DOT4(p1, wB0, h4) DOT4(p2, wC0, h4) DOT4(p3, wD0, h4) \
    h4 = hp[1]; DOT4(p0, wA1, h4) DOT4(p1, wB1, h4) DOT4(p2, wC1, h4) DOT4(p3, wD1, h4) \
    h4 = hp[2]; DOT4(p0, wA2, h4) DOT4(p1, wB2, h4) DOT4(p2, wC2, h4) DOT4(p3, wD2, h4) \
    h4 = hp[3]; DOT4(p0, wA3, h4) DOT4(p1, wB3, h4) DOT4(p2, wC3, h4) DOT4(p3, wD3, h4) \
    h4 = hp[4]; DOT4(p0, wA4, h4) DOT4(p1, wB4, h4) DOT4(p2, wC4, h4) DOT4(p3, wD4, h4) \
    p0 += __shfl_xor(p0, 1);                                                   \
    p1 += __shfl_xor(p1, 1);                                                   \
    p2 += __shfl_xor(p2, 1);                                                   \
    p3 += __shfl_xor(p3, 1);                                                   \
    float gi = sigmoid_f(p0), gf = sigmoid_f(p1);                              \
    float gg = tanh_f(p2),    go = sigmoid_f(p3);                              \
    c_st = fmaf(gf, c_st, gi * gg);                                            \
    float hn = go * tanh_f(c_st);                                              \
    if (h == 0) h_s[cur ^ 1][r][j] = hn;                                       \
} while (0)

// x-path coefficients for one gate (embedding collapsed)
#define XCOEF(g, fAv, fCv, f0v, f1v, f2v) {                                    \
    const int row_ = (g) * HID + j;                                            \
    const float* wr_ = W_ih + row_ * 23;                                       \
    float a_ = 0.0f, cc_ = b_ih[row_] + b_hh[row_];                            \
    _Pragma("unroll")                                                          \
    for (int e = 0; e < 20; e++) {                                             \
        float wv_ = wr_[e];                                                    \
        a_  = fmaf(wv_, W_emb[e], a_);                                         \
        cc_ = fmaf(wv_, b_emb[e], cc_);                                        \
    }                                                                          \
    fAv = a_; fCv = cc_; f0v = wr_[20]; f1v = wr_[21]; f2v = wr_[22];          \
}

__launch_bounds__(NTHREADS, 1)
__global__ void deepar_kernel(const float* __restrict__ z1,
                              const float* __restrict__ xc,
                              const float* __restrict__ W_emb,
                              const float* __restrict__ b_emb,
                              const float* __restrict__ W_ih,
                              const float* __restrict__ b_ih,
                              const float* __restrict__ W_hh,
                              const float* __restrict__ b_hh,
                              const float* __restrict__ W_mu,
                              const float* __restrict__ b_mu,
                              const float* __restrict__ W_sig,
                              const float* __restrict__ b_sig,
                              float* __restrict__ out) {
    __shared__ __align__(16) float z1_s[ROWS][CR_LEN];
    __shared__ __align__(16) float xc_s[ROWS][XC_LEN];
    __shared__ __align__(16) float h_s[2][ROWS][HID];
    __shared__ float eps_s[ROWS][PR_LEN];
    __shared__ float y_s[ROWS];
    __shared__ float v_s[ROWS], iv_s[ROWS];
    __shared__ __align__(16) float wmu_s[HID];
    __shared__ __align__(16) float wsg_s[HID];
    __shared__ float bmu_s, bsg_s;

    const int tid = threadIdx.x;
    const int r   = tid / 80;            // row in block (0..3)
    const int u   = tid - r * 80;        // 0..79
    const int j   = u >> 1;              // unit 0..39
    const int h   = u & 1;               // k-half 0/1 (partner = lane^1)
    const int b_base = blockIdx.x * ROWS;
    const int b   = b_base + r;

    // ---- cooperative staging ----
    {
        const float4* s1 = (const float4*)(z1 + (size_t)b_base * CR_LEN);
        float4* d1 = (float4*)&z1_s[0][0];
        for (int idx = tid; idx < ROWS * (CR_LEN / 4); idx += NTHREADS) d1[idx] = s1[idx];
        const float4* s2 = (const float4*)(xc + (size_t)b_base * XC_LEN);
        float4* d2 = (float4*)&xc_s[0][0];
        for (int idx = tid; idx < ROWS * (XC_LEN / 4); idx += NTHREADS) d2[idx] = s2[idx];
    }
    if (tid < HID)                 wmu_s[tid] = W_mu[tid];
    else if (tid < 2 * HID)        wsg_s[tid - HID] = W_sig[tid - HID];
    else if (tid == 2 * HID)       bmu_s = b_mu[0];
    else if (tid == 2 * HID + 1)   bsg_s = b_sig[0];

    // ---- x-path coefficients, h-selected:
    //  h==0: partial = fC + fA*z1n + f0*xa ;  h==1: partial = f1*xb + f2*xv
    float bA, bB, bC, bD, cA0, cA1, cA2, cA3, cB0, cB1, cB2, cB3;
    {
        float fA_, fC_, f0_, f1_, f2_;
        XCOEF(0, fA_, fC_, f0_, f1_, f2_)
        bA = h ? 0.0f : fC_; cA0 = h ? f1_ : fA_; cB0 = h ? f2_ : f0_;
        XCOEF(1, fA_, fC_, f0_, f1_, f2_)
        bB = h ? 0.0f : fC_; cA1 = h ? f1_ : fA_; cB1 = h ? f2_ : f0_;
        XCOEF(2, fA_, fC_, f0_, f1_, f2_)
        bC = h ? 0.0f : fC_; cA2 = h ? f1_ : fA_; cB2 = h ? f2_ : f0_;
        XCOEF(3, fA_, fC_, f0_, f1_, f2_)
        bD = h ? 0.0f : fC_; cA3 = h ? f1_ : fA_; cB3 = h ? f2_ : f0_;
    }

    // ---- my W_hh half-rows: 4 gates x 20 weights = 20 pinned float4 ----
    const float4* pw = (const float4*)W_hh;
    LOADW5(wA, (0 * HID + j) * 10 + 5 * h)
    LOADW5(wB, (1 * HID + j) * 10 + 5 * h)
    LOADW5(wC, (2 * HID + j) * 10 + 5 * h)
    LOADW5(wD, (3 * HID + j) * 10 + 5 * h)

    __syncthreads();   // staging ready

    // ---- v per row (threads 0..3) ----
    if (tid < ROWS) {
        float s = 0.0f;
#pragma unroll
        for (int q = 0; q < CR_LEN / 4; q++) {
            float4 zz = *(const float4*)&z1_s[tid][4 * q];
            s += zz.x + zz.y + zz.z + zz.w;
        }
        float v = s * (1.0f / (float)CR_LEN) + 1.0f;
        v_s[tid]  = v;
        iv_s[tid] = 1.0f / v;
    }

    // ---- eps (96 values, threads 0..95) ----
    if (tid < ROWS * PR_LEN) {
        const int row_ = tid / PR_LEN;
        const int tt   = tid - row_ * PR_LEN;
        unsigned i = (unsigned)tt * B_TOTAL + (unsigned)(b_base + row_);
        unsigned o0, o1;
        threefry2x32(0u, 42u, 0u, i, o0, o1);
        unsigned bits = o0 ^ o1;
        float f = __uint_as_float((bits >> 9) | 0x3F800000u) - 1.0f;
        const float lo = -0.99999994f;
        float uu = fmaxf(lo, fmaf(f, 2.0f, lo));
        eps_s[row_][tt] = 1.41421356237f * erfinv_f(uu);
    }

    if (h == 0) h_s[0][r][j] = 0.0f;   // 160 threads cover 4x40
    float c_st = 0.0f;
    __syncthreads();

    const float iv = iv_s[r];
    int cur = 0;

    // ---- conditioning: t = 0..166, one barrier per step ----
    for (int t = 0; t < CR_LEN - 1; t++) {
        const int xo = 3 * (t + 1);
        float xin0 = h ? xc_s[r][xo + 1] : z1_s[r][t] * iv;
        float xin1 = h ? xc_s[r][xo + 2] : xc_s[r][xo + 0];
        KSTEP(xin0, xin1);
        __syncthreads();
        cur ^= 1;
    }

    if (tid < ROWS) y_s[tid] = z1_s[tid][CR_LEN - 1];
    __syncthreads();

    // ---- prediction: t = 0..23 ----
    for (int t = 0; t < PR_LEN; t++) {
        const int xo = 3 * (CR_LEN + t);
        float xin0 = h ? xc_s[r][xo + 1] : y_s[r] * iv;
        float xin1 = h ? xc_s[r][xo + 2] : xc_s[r][xo + 0];
        KSTEP(xin0, xin1);
        __syncthreads();
        cur ^= 1;
        if (u == 0) {   // 4 threads: one per row
            float mu = bmu_s, sp = bsg_s;
            const float4* hp = (const float4*)&h_s[cur][r][0];
#pragma unroll
            for (int q = 0; q < 10; q++) {
                float4 h4 = hp[q];
                float4 wm = *(const float4*)&wmu_s[4 * q];
                float4 ws = *(const float4*)&wsg_s[4 * q];
                mu = fmaf(wm.x, h4.x, mu); mu = fmaf(wm.y, h4.y, mu);
                mu = fmaf(wm.z, h4.z, mu); mu = fmaf(wm.w, h4.w, mu);
                sp = fmaf(ws.x, h4.x, sp); sp = fmaf(ws.y, h4.y, sp);
                sp = fmaf(ws.z, h4.z, sp); sp = fmaf(ws.w, h4.w, sp);
            }
            float sigma = fmaxf(sp, 0.0f) + log1pf(__expf(-fabsf(sp)));
            float y = fmaf(sigma, eps_s[r][t], mu);
            y_s[r] = y;
            const float vv = v_s[r];
            const int ob = b * PR_LEN + t;
            float poison = (b == 0 && t == 0) ? kat_poison() : 0.0f;
            out[ob]                  = y * vv + poison;
            out[OUT_STRIDE + ob]     = mu * vv;
            out[2 * OUT_STRIDE + ob] = sigma * vv;
        }
        __syncthreads();   // y_s ready for next step
    }
}

extern "C" void kernel_launch(void* const* d_in, const int* in_sizes, int n_in,
                              void* d_out, int out_size, void* d_ws, size_t ws_size,
                              hipStream_t stream) {
    const float* z1    = (const float*)d_in[0];
    const float* xc    = (const float*)d_in[1];
    const float* W_emb = (const float*)d_in[2];
    const float* b_emb = (const float*)d_in[3];
    const float* W_ih  = (const float*)d_in[4];
    const float* b_ih  = (const float*)d_in[5];
    const float* W_hh  = (const float*)d_in[6];
    const float* b_hh  = (const float*)d_in[7];
    const float* W_mu  = (const float*)d_in[8];
    const float* b_mu  = (const float*)d_in[9];
    const float* W_sig = (const float*)d_in[10];
    const float* b_sig = (const float*)d_in[11];
    float* out = (float*)d_out;

    dim3 grid(B_TOTAL / ROWS);   // 2048
    dim3 block(NTHREADS);        // 320
    deepar_kernel<<<grid, block, 0, stream>>>(z1, xc, W_emb, b_emb, W_ih, b_ih,
                                              W_hh, b_hh, W_mu, b_mu, W_sig, b_sig,
                                              out);
}

// Round 12
// 578.709 us; speedup vs baseline: 1.7883x; 1.7883x over previous
//
#include <hip/hip_runtime.h>

#define B_TOTAL   8192
#define CR_LEN    168
#define PR_LEN    24
#define HID       40
#define NB        16               // batch rows per block
#define NTH       640              // 10 waves; wave w owns M-tile w (gate-rows 16w..16w+15)
#define XC_LEN    ((CR_LEN + PR_LEN) * 3)   // 576
#define OUT_STRIDE (B_TOTAL * PR_LEN)       // 196608
#define PSTR      17               // pre_s row stride (bank-spread)
#define HSTR      17               // hp_s row stride

typedef __attribute__((ext_vector_type(8))) short short8;
typedef __attribute__((ext_vector_type(4))) float f32x4;

__device__ __forceinline__ float fast_rcp(float x) { return __builtin_amdgcn_rcpf(x); }
__device__ __forceinline__ float sigmoid_f(float x) { return fast_rcp(1.0f + __expf(-x)); }
__device__ __forceinline__ float tanh_f(float x) {
    float ax = fabsf(x);
    float e  = __expf(-2.0f * ax);
    float r  = (1.0f - e) * fast_rcp(1.0f + e);
    return copysignf(r, x);
}
__device__ __forceinline__ unsigned rotl32(unsigned x, int d) { return (x << d) | (x >> (32 - d)); }

// JAX threefry2x32 (20 rounds) — HW-KAT-verified (round 2)
__device__ __forceinline__ void threefry2x32(unsigned k0, unsigned k1,
                                             unsigned c0, unsigned c1,
                                             unsigned& o0, unsigned& o1) {
    const unsigned k2 = 0x1BD11BDAu ^ k0 ^ k1;
    unsigned x0 = c0 + k0, x1 = c1 + k1;
#define TF_R(rr) { x0 += x1; x1 = rotl32(x1, (rr)); x1 ^= x0; }
    TF_R(13) TF_R(15) TF_R(26) TF_R(6)  x0 += k1; x1 += k2 + 1u;
    TF_R(17) TF_R(29) TF_R(16) TF_R(24) x0 += k2; x1 += k0 + 2u;
    TF_R(13) TF_R(15) TF_R(26) TF_R(6)  x0 += k0; x1 += k1 + 3u;
    TF_R(17) TF_R(29) TF_R(16) TF_R(24) x0 += k1; x1 += k2 + 4u;
    TF_R(13) TF_R(15) TF_R(26) TF_R(6)  x0 += k2; x1 += k0 + 5u;
#undef TF_R
    o0 = x0; o1 = x1;
}

__device__ __forceinline__ float erfinv_f(float x) {
    float w = -__logf(fmaf(-x, x, 1.0f));
    float p;
    if (w < 5.0f) {
        w -= 2.5f;
        p = 2.81022636e-08f;
        p = fmaf(p, w, 3.43273939e-07f);
        p = fmaf(p, w, -3.5233877e-06f);
        p = fmaf(p, w, -4.39150654e-06f);
        p = fmaf(p, w, 0.00021858087f);
        p = fmaf(p, w, -0.00125372503f);
        p = fmaf(p, w, -0.00417768164f);
        p = fmaf(p, w, 0.246640727f);
        p = fmaf(p, w, 1.50140941f);
    } else {
        w = sqrtf(w) - 3.0f;
        p = -0.000200214257f;
        p = fmaf(p, w, 0.000100950558f);
        p = fmaf(p, w, 0.00134934322f);
        p = fmaf(p, w, -0.00367342844f);
        p = fmaf(p, w, 0.00573950773f);
        p = fmaf(p, w, -0.0076224613f);
        p = fmaf(p, w, 0.00943887047f);
        p = fmaf(p, w, 1.00167406f);
        p = fmaf(p, w, 2.83297682f);
    }
    return p * x;
}

__device__ __forceinline__ float kat_poison() {
    float poison = 0.0f;
    unsigned o0, o1;
    threefry2x32(0u, 0u, 0u, 0u, o0, o1);
    bool ok1 = (o0 == 0x6b200159u) && (o1 == 0x99ba4efeu);
    threefry2x32(0xFFFFFFFFu, 0xFFFFFFFFu, 0xFFFFFFFFu, 0xFFFFFFFFu, o0, o1);
    bool ok2 = (o0 == 0x1cb996fcu) && (o1 == 0xbb002be7u);
    if (!(ok1 && ok2)) poison += 4096.0f;
    threefry2x32(0x13198a2eu, 0x03707344u, 0x243f6a88u, 0x85a308d3u, o0, o1);
    bool ok3 = (o0 == 0xc4923a9cu) && (o1 == 0x483df7a0u);
    if (!ok3) poison += 8192.0f;
    return poison;
}

// ---- bf16 split helpers (RNE) ----
__device__ __forceinline__ unsigned f2bf(float x) {
    unsigned u = __float_as_uint(x);
    return (u + 0x7FFFu + ((u >> 16) & 1u)) >> 16;
}
__device__ __forceinline__ float bf2f(unsigned s) { return __uint_as_float(s << 16); }
__device__ __forceinline__ unsigned pk2(unsigned a, unsigned b) { return (a & 0xFFFFu) | (b << 16); }
__device__ __forceinline__ unsigned pkl(unsigned a, unsigned b) { return (a >> 16) | (b & 0xFFFF0000u); }
__device__ __forceinline__ void splitpair(float x0, float x1, unsigned& hi, unsigned& lo) {
    unsigned h0 = f2bf(x0), h1 = f2bf(x1);
    unsigned l0 = f2bf(x0 - bf2f(h0)), l1 = f2bf(x1 - bf2f(h1));
    hi = pk2(h0, h1); lo = pk2(l0, l1);
}

union U4S8 { uint4 u; short8 s; };
__device__ __forceinline__ short8 as_s8(uint4 u) { U4S8 c; c.u = u; return c.s; }

#define KEEPI4(q) asm volatile("" : "+v"((q).x), "+v"((q).y), "+v"((q).z), "+v"((q).w))
#define MM(a, b, c) (c) = __builtin_amdgcn_mfma_f32_16x16x32_bf16(as_s8(a), as_s8(b), (c), 0, 0, 0)

// x-path coefficients for one gate (embedding collapsed), unit index J
#define XCOEF(g, J, fAv, fCv, f0v, f1v, f2v) {                                 \
    const int row_ = (g) * HID + (J);                                          \
    const float* wr_ = W_ih + row_ * 23;                                       \
    float a_ = 0.0f, cc_ = b_ih[row_] + b_hh[row_];                            \
    _Pragma("unroll")                                                          \
    for (int e = 0; e < 20; e++) {                                             \
        float wv_ = wr_[e];                                                    \
        a_  = fmaf(wv_, W_emb[e], a_);                                         \
        cc_ = fmaf(wv_, b_emb[e], cc_);                                        \
    }                                                                          \
    fAv = a_; fCv = cc_; f0v = wr_[20]; f1v = wr_[21]; f2v = wr_[22];          \
}

// rebuild B fragments (next-step h) from hp_s; lane: col=lane&15, k=(lane>>4)*8+e
#define REBUILD() do {                                                         \
    unsigned q0 = hp_s[(kg * 8 + 0) * HSTR + col];                             \
    unsigned q1 = hp_s[(kg * 8 + 1) * HSTR + col];                             \
    unsigned q2 = hp_s[(kg * 8 + 2) * HSTR + col];                             \
    unsigned q3 = hp_s[(kg * 8 + 3) * HSTR + col];                             \
    unsigned q4 = hp_s[(kg * 8 + 4) * HSTR + col];                             \
    unsigned q5 = hp_s[(kg * 8 + 5) * HSTR + col];                             \
    unsigned q6 = hp_s[(kg * 8 + 6) * HSTR + col];                             \
    unsigned q7 = hp_s[(kg * 8 + 7) * HSTR + col];                             \
    Bh0 = make_uint4(pk2(q0, q1), pk2(q2, q3), pk2(q4, q5), pk2(q6, q7));      \
    Bl0 = make_uint4(pkl(q0, q1), pkl(q2, q3), pkl(q4, q5), pkl(q6, q7));      \
    Bh1 = make_uint4(0, 0, 0, 0); Bl1 = make_uint4(0, 0, 0, 0);                \
    if (kg == 0) {                                                             \
        unsigned r0 = hp_s[(32 + 0) * HSTR + col];                             \
        unsigned r1 = hp_s[(32 + 1) * HSTR + col];                             \
        unsigned r2 = hp_s[(32 + 2) * HSTR + col];                             \
        unsigned r3 = hp_s[(32 + 3) * HSTR + col];                             \
        unsigned r4 = hp_s[(32 + 4) * HSTR + col];                             \
        unsigned r5 = hp_s[(32 + 5) * HSTR + col];                             \
        unsigned r6 = hp_s[(32 + 6) * HSTR + col];                             \
        unsigned r7 = hp_s[(32 + 7) * HSTR + col];                             \
        Bh1 = make_uint4(pk2(r0, r1), pk2(r2, r3), pk2(r4, r5), pk2(r6, r7));  \
        Bl1 = make_uint4(pkl(r0, r1), pkl(r2, r3), pkl(r4, r5), pkl(r6, r7));  \
    }                                                                          \
} while (0)

// MFMA phase + pre_s scatter (C/D layout: col=lane&15, row=(lane>>4)*4+reg)
#define MFMA_PHASE() do {                                                      \
    f32x4 acc = {0.0f, 0.0f, 0.0f, 0.0f};                                      \
    MM(A0h, Bh0, acc); MM(A0h, Bl0, acc); MM(A0l, Bh0, acc);                   \
    MM(A1h, Bh1, acc); MM(A1h, Bl1, acc); MM(A1l, Bh1, acc);                   \
    const int rbase = 16 * wv + kg * 4;                                        \
    pre_s[(rbase + 0) * PSTR + col] = acc[0];                                  \
    pre_s[(rbase + 1) * PSTR + col] = acc[1];                                  \
    pre_s[(rbase + 2) * PSTR + col] = acc[2];                                  \
    pre_s[(rbase + 3) * PSTR + col] = acc[3];                                  \
} while (0)

// update phase: this thread owns (unit jj, batch bb)
#define UPDATE_PHASE(Z1N, XO) do {                                             \
    const float* xp_ = &xc_s[bb * XC_LEN + (XO)];                              \
    float xa_ = xp_[0], xb_ = xp_[1], xv_ = xp_[2];                            \
    float p0 = pre_s[(0 * HID + jj) * PSTR + bb] + fmaf(fA0, (Z1N), fC0);      \
    float p1 = pre_s[(1 * HID + jj) * PSTR + bb] + fmaf(fA1, (Z1N), fC1);      \
    float p2 = pre_s[(2 * HID + jj) * PSTR + bb] + fmaf(fA2, (Z1N), fC2);      \
    float p3 = pre_s[(3 * HID + jj) * PSTR + bb] + fmaf(fA3, (Z1N), fC3);      \
    p0 = fmaf(f00, xa_, p0); p1 = fmaf(f01, xa_, p1);                          \
    p2 = fmaf(f02, xa_, p2); p3 = fmaf(f03, xa_, p3);                          \
    p0 = fmaf(f10, xb_, p0); p1 = fmaf(f11, xb_, p1);                          \
    p2 = fmaf(f12, xb_, p2); p3 = fmaf(f13, xb_, p3);                          \
    p0 = fmaf(f20, xv_, p0); p1 = fmaf(f21, xv_, p1);                          \
    p2 = fmaf(f22, xv_, p2); p3 = fmaf(f23, xv_, p3);                          \
    float gi = sigmoid_f(p0), gf = sigmoid_f(p1);                              \
    float gg = tanh_f(p2),    go = sigmoid_f(p3);                              \
    c_st = fmaf(gf, c_st, gi * gg);                                            \
    float hn = go * tanh_f(c_st);                                              \
    unsigned hh_ = f2bf(hn);                                                   \
    unsigned hl_ = f2bf(hn - bf2f(hh_));                                       \
    hp_s[jj * HSTR + bb] = hh_ | (hl_ << 16);                                  \
} while (0)

__launch_bounds__(NTH, 5)
__global__ void deepar_kernel(const float* __restrict__ z1,
                              const float* __restrict__ xc,
                              const float* __restrict__ W_emb,
                              const float* __restrict__ b_emb,
                              const float* __restrict__ W_ih,
                              const float* __restrict__ b_ih,
                              const float* __restrict__ W_hh,
                              const float* __restrict__ b_hh,
                              const float* __restrict__ W_mu,
                              const float* __restrict__ b_mu,
                              const float* __restrict__ W_sig,
                              const float* __restrict__ b_sig,
                              float* __restrict__ out) {
    __shared__ __align__(16) float z1_s[NB * CR_LEN];
    __shared__ __align__(16) float xc_s[NB * XC_LEN];
    __shared__ __align__(16) float pre_s[4 * HID * PSTR];   // 160 x 17
    __shared__ unsigned hp_s[HID * HSTR];                   // packed bf16 hi|lo<<16
    __shared__ float eps_s[NB * PR_LEN];
    __shared__ float y_s[NB], v_s[NB], iv_s[NB];
    __shared__ __align__(16) float wmu_s[HID];
    __shared__ __align__(16) float wsg_s[HID];
    __shared__ float bmu_s, bsg_s;

    const int tid  = threadIdx.x;
    const int wv   = tid >> 6;        // wave / M-tile 0..9
    const int lane = tid & 63;
    const int col  = lane & 15;       // MFMA col (batch) / A row
    const int kg   = lane >> 4;       // k-group
    const int jj   = tid >> 4;        // update: unit 0..39
    const int bb   = tid & 15;        // update: batch row 0..15
    const int b_base = blockIdx.x * NB;

    // ---- cooperative staging ----
    {
        const float4* s1 = (const float4*)(z1 + (size_t)b_base * CR_LEN);
        float4* d1 = (float4*)&z1_s[0];
        for (int idx = tid; idx < NB * (CR_LEN / 4); idx += NTH) d1[idx] = s1[idx];
        const float4* s2 = (const float4*)(xc + (size_t)b_base * XC_LEN);
        float4* d2 = (float4*)&xc_s[0];
        for (int idx = tid; idx < NB * (XC_LEN / 4); idx += NTH) d2[idx] = s2[idx];
    }
    if (tid < HID)                 wmu_s[tid] = W_mu[tid];
    else if (tid < 2 * HID)        wsg_s[tid - HID] = W_sig[tid - HID];
    else if (tid == 2 * HID)       bmu_s = b_mu[0];
    else if (tid == 2 * HID + 1)   bsg_s = b_sig[0];

    // ---- x-path coefficients for my update unit jj (20 regs) ----
    float fA0, fC0, f00, f10, f20;
    float fA1, fC1, f01, f11, f21;
    float fA2, fC2, f02, f12, f22;
    float fA3, fC3, f03, f13, f23;
    XCOEF(0, jj, fA0, fC0, f00, f10, f20)
    XCOEF(1, jj, fA1, fC1, f01, f11, f21)
    XCOEF(2, jj, fA2, fC2, f02, f12, f22)
    XCOEF(3, jj, fA3, fC3, f03, f13, f23)

    // ---- A fragments: W_hh M-tile wv, split-bf16 hi/lo, PINNED (loaded once) ----
    uint4 A0h, A0l, A1h, A1l;
    {
        const int arow = 16 * wv + col;          // gate-row (A row = lane&15)
        const float* wr = W_hh + arow * HID;
        const int k0 = kg * 8;
        splitpair(wr[k0 + 0], wr[k0 + 1], A0h.x, A0l.x);
        splitpair(wr[k0 + 2], wr[k0 + 3], A0h.y, A0l.y);
        splitpair(wr[k0 + 4], wr[k0 + 5], A0h.z, A0l.z);
        splitpair(wr[k0 + 6], wr[k0 + 7], A0h.w, A0l.w);
        A1h = make_uint4(0, 0, 0, 0); A1l = make_uint4(0, 0, 0, 0);
        if (kg == 0) {                           // k = 32..39 real, rest zero-pad
            splitpair(wr[32], wr[33], A1h.x, A1l.x);
            splitpair(wr[34], wr[35], A1h.y, A1l.y);
            splitpair(wr[36], wr[37], A1h.z, A1l.z);
            splitpair(wr[38], wr[39], A1h.w, A1l.w);
        }
        KEEPI4(A0h); KEEPI4(A0l); KEEPI4(A1h); KEEPI4(A1l);
    }

    __syncthreads();   // staging ready

    // ---- v per batch row ----
    if (tid < NB) {
        float s = 0.0f;
#pragma unroll
        for (int q = 0; q < CR_LEN / 4; q++) {
            float4 zz = *(const float4*)&z1_s[tid * CR_LEN + 4 * q];
            s += zz.x + zz.y + zz.z + zz.w;
        }
        float v = s * (1.0f / (float)CR_LEN) + 1.0f;
        v_s[tid]  = v;
        iv_s[tid] = 1.0f / v;
    }

    // ---- eps (384 values) ----
    if (tid < NB * PR_LEN) {
        const int row_ = tid / PR_LEN;
        const int tt   = tid - row_ * PR_LEN;
        unsigned i = (unsigned)tt * B_TOTAL + (unsigned)(b_base + row_);
        unsigned o0, o1;
        threefry2x32(0u, 42u, 0u, i, o0, o1);
        unsigned bits = o0 ^ o1;
        float f = __uint_as_float((bits >> 9) | 0x3F800000u) - 1.0f;
        const float lo = -0.99999994f;
        float uu = fmaxf(lo, fmaf(f, 2.0f, lo));
        eps_s[row_ * PR_LEN + tt] = 1.41421356237f * erfinv_f(uu);
    }
    __syncthreads();   // v/eps ready

    const float iv = iv_s[bb];
    float c_st = 0.0f;
    uint4 Bh0 = make_uint4(0, 0, 0, 0), Bl0 = make_uint4(0, 0, 0, 0);
    uint4 Bh1 = make_uint4(0, 0, 0, 0), Bl1 = make_uint4(0, 0, 0, 0);   // h0 = 0

    // ---- conditioning: t = 0..166 ----
    for (int t = 0; t < CR_LEN - 1; t++) {
        MFMA_PHASE();
        __syncthreads();
        UPDATE_PHASE(z1_s[bb * CR_LEN + t] * iv, 3 * (t + 1));
        __syncthreads();
        REBUILD();
    }

    if (tid < NB) y_s[tid] = z1_s[tid * CR_LEN + (CR_LEN - 1)];

    // ---- prediction: t = 0..23 ----
    for (int t = 0; t < PR_LEN; t++) {
        MFMA_PHASE();
        __syncthreads();
        UPDATE_PHASE(y_s[bb] * iv, 3 * (CR_LEN + t));
        __syncthreads();
        REBUILD();
        if (tid < NB) {            // heads: one thread per batch row
            const int b = tid;
            float mu = bmu_s, sp = bsg_s;
#pragma unroll
            for (int q = 0; q < HID; q++) {
                unsigned u = hp_s[q * HSTR + b];
                float h = bf2f(u & 0xFFFFu) + bf2f(u >> 16);
                mu = fmaf(wmu_s[q], h, mu);
                sp = fmaf(wsg_s[q], h, sp);
            }
            float sigma = fmaxf(sp, 0.0f) + log1pf(__expf(-fabsf(sp)));
            float y = fmaf(sigma, eps_s[b * PR_LEN + t], mu);
            y_s[b] = y;
            const float vv = v_s[b];
            const int bglob = b_base + b;
            const int ob = bglob * PR_LEN + t;
            float poison = (bglob == 0 && t == 0) ? kat_poison() : 0.0f;
            out[ob]                  = y * vv + poison;
            out[OUT_STRIDE + ob]     = mu * vv;
            out[2 * OUT_STRIDE + ob] = sigma * vv;
        }
        // next iteration's post-MFMA barrier orders y_s for the update phase
    }
}

extern "C" void kernel_launch(void* const* d_in, const int* in_sizes, int n_in,
                              void* d_out, int out_size, void* d_ws, size_t ws_size,
                              hipStream_t stream) {
    const float* z1    = (const float*)d_in[0];
    const float* xc    = (const float*)d_in[1];
    const float* W_emb = (const float*)d_in[2];
    const float* b_emb = (const float*)d_in[3];
    const float* W_ih  = (const float*)d_in[4];
    const float* b_ih  = (const float*)d_in[5];
    const float* W_hh  = (const float*)d_in[6];
    const float* b_hh  = (const float*)d_in[7];
    const float* W_mu  = (const float*)d_in[8];
    const float* b_mu  = (const float*)d_in[9];
    const float* W_sig = (const float*)d_in[10];
    const float* b_sig = (const float*)d_in[11];
    float* out = (float*)d_out;

    dim3 grid(B_TOTAL / NB);   // 512 blocks — 2 per CU
    dim3 block(NTH);           // 640 threads (10 waves)
    deepar_kernel<<<grid, block, 0, stream>>>(z1, xc, W_emb, b_emb, W_ih, b_ih,
                                              W_hh, b_hh, W_mu, b_mu, W_sig, b_sig,
                                              out);
}